// Round 5
// baseline (980.276 us; speedup 1.0000x reference)
//
#include <hip/hip_runtime.h>

// ResidualSimVQ eval forward — R5: fused 4-row phases + DMA double-buffered Wn.
// implicit_c = CB_c @ Wn^T + b (rank 8) => argmin needs only p = res@[Wn|b].
// rot = A*res + C*zq (wave-uniform A,C); res' = (1-A)res - C*zq;
// ns2 by recurrence, nt2 from qtab, pz = pb + cb.p.
// f32 scoring + gap-triggered exact-f64 fallback (p stays f64: fallback exact).
// Numerics: accumulation orders identical to the passing R4; only the rotation
// scalars use rsqrt (1e-15-class change, decisions unaffected).
// commit is wave-uniform -> lane 0's copy IS the wave total (no reduction).

#define NB  16
#define DD  512
#define TT  2048
#define NCB 9
#define CS  1024
#define CD  8
#define KK  9   // CD + 1: row 8 of the table is the bias b
#define NBLK (NB * (TT / 16))   // 2048 k_main blocks
#define STGB (KK * DD * 8)      // 36864 B per stage table

#define WS_WN_OFF  16384                               // f64 [Wn|b], k-major
#define WS_Q_OFF   (WS_WN_OFF + (size_t)NCB*KK*DD*8)   // f64 ||implicit||^2
#define WS_QF_OFF  (WS_Q_OFF  + (size_t)NCB*CS*8)      // f32 copy

__device__ __forceinline__ void ld_lds16(const void* g, void* l) {
  __builtin_amdgcn_global_load_lds(
      (const __attribute__((address_space(1))) void*)g,
      (__attribute__((address_space(3))) void*)l, 16, 0, 0);
}

__global__ void k_wn(const float* __restrict__ V, const float* __restrict__ g,
                     const float* __restrict__ bp, double* __restrict__ wn) {
  int gid = blockIdx.x * 256 + threadIdx.x;
  if (gid >= NCB * DD) return;
  int i = gid / DD, d = gid % DD;
  const float* vp = V + (size_t)gid * CD;
  double v[CD], s = 0.0;
#pragma unroll
  for (int k = 0; k < CD; k++) { v[k] = (double)vp[k]; s = fma(v[k], v[k], s); }
  double den = fmax(sqrt(s), 1e-12);
  double gg = (double)g[gid];
#pragma unroll
  for (int k = 0; k < CD; k++)
    wn[((size_t)i * KK + k) * DD + d] = gg * v[k] / den;
  wn[((size_t)i * KK + CD) * DD + d] = (double)bp[gid];   // bias row
}

__global__ void k_q(const float* __restrict__ CBp, const float* __restrict__ bp,
                    const double* __restrict__ wn,
                    double* __restrict__ q, float* __restrict__ qf) {
  int wid = blockIdx.x * 4 + (threadIdx.x >> 6);
  int lane = threadIdx.x & 63;
  int i = wid / CS, c = wid % CS;
  const float* cb = CBp + (size_t)(i * CS + c) * CD;
  double cbv[CD];
#pragma unroll
  for (int k = 0; k < CD; k++) cbv[k] = (double)cb[k];
  const double* wnp = wn + (size_t)i * KK * DD;
  const float* bb = bp + (size_t)i * DD;
  double acc = 0.0;
#pragma unroll
  for (int j = 0; j < 8; j++) {
    int d = j * 64 + lane;
    double imp = (double)bb[d];
#pragma unroll
    for (int k = 0; k < CD; k++) imp = fma(cbv[k], wnp[(size_t)k * DD + d], imp);
    acc = fma(imp, imp, acc);
  }
#pragma unroll
  for (int o = 32; o; o >>= 1) acc += __shfl_xor(acc, o, 64);
  if (lane == 0) { q[wid] = acc; qf[wid] = (float)acc; }
}

__launch_bounds__(256, 2)
__global__ void k_main(const float* __restrict__ z, const float* __restrict__ CBp,
                       const double* __restrict__ wn, const double* __restrict__ qtab,
                       const float* __restrict__ qftab,
                       float* __restrict__ out_zq, float* __restrict__ out_codes,
                       double* __restrict__ partials) {
  __shared__ __align__(16) double buf[2][KK * DD];   // 2 x 36864 B
  __shared__ double cbuf[4];
  float* tile = (float*)buf[1];                      // 34816 B fits in buf[1]

  const int tid = threadIdx.x, lane = tid & 63, w = tid >> 6;
  const int bb = blockIdx.x >> 7, tg = blockIdx.x & 127;
  const int t0 = tg * 16;
  const float* zb = z + (size_t)bb * DD * TT + t0;
  const char* wnb = (const char*)wn;

  // ---- prologue: DMA stage-0 table into buf[0]; transpose z tile in buf[1] --
#pragma unroll
  for (int m = 0; m < 9; m++)
    ld_lds16(wnb + (size_t)w * 9216 + m * 1024 + lane * 16,
             (char*)buf[0] + w * 9216 + m * 1024);
#pragma unroll
  for (int m = 0; m < 8; m++) {
    int F = tid + m * 256, d = F >> 2, qq = F & 3;
    const float4 v = *(const float4*)(zb + (size_t)d * TT + qq * 4);
    tile[d * 17 + qq * 4 + 0] = v.x; tile[d * 17 + qq * 4 + 1] = v.y;
    tile[d * 17 + qq * 4 + 2] = v.z; tile[d * 17 + qq * 4 + 3] = v.w;
  }
  __syncthreads();   // tile written; stage-0 DMA drained (vmcnt 0 at barrier)

  double res[4][8], ns2[4];
#pragma unroll
  for (int r = 0; r < 4; r++) {
    double s = 0.0;
#pragma unroll
    for (int j = 0; j < 8; j++) {
      res[r][j] = (double)tile[(j * 64 + lane) * 17 + (w * 4 + r)];
      s = fma(res[r][j], res[r][j], s);
    }
    ns2[r] = s;
  }
#pragma unroll
  for (int o = 32; o; o >>= 1)
#pragma unroll
    for (int r = 0; r < 4; r++) ns2[r] += __shfl_xor(ns2[r], o, 64);
  __syncthreads();   // tile reads done -> buf[1] free for stage-1 DMA

  double commit = 0.0;

  for (int i = 0; i < NCB; i++) {
    const double* wcur = buf[i & 1];
    // ---- prefetch next stage table (DMA, overlapped with compute) ----
    if (i < NCB - 1) {
      const char* src = wnb + (size_t)(i + 1) * STGB;
#pragma unroll
      for (int m = 0; m < 9; m++)
        ld_lds16(src + (size_t)w * 9216 + m * 1024 + lane * 16,
                 (char*)buf[(i + 1) & 1] + w * 9216 + m * 1024);
    }

    const float* cbbase = CBp + (size_t)i * CS * CD;
    const float* qfb = qftab + i * CS;
    const double* qb = qtab + i * CS;

    // ---- phase 1: p[r][k] = res . [Wn|b], all 4 rows, one pass ----
    double p[4][KK];
#pragma unroll
    for (int r = 0; r < 4; r++)
#pragma unroll
      for (int k = 0; k < KK; k++) p[r][k] = 0.0;
#pragma unroll
    for (int j = 0; j < 8; j++) {
      int d = j * 64 + lane;
      double wv[KK];
#pragma unroll
      for (int k = 0; k < KK; k++) wv[k] = wcur[k * DD + d];
#pragma unroll
      for (int r = 0; r < 4; r++) {
        double rv = res[r][j];
#pragma unroll
        for (int k = 0; k < KK; k++) p[r][k] = fma(rv, wv[k], p[r][k]);
      }
    }
#pragma unroll
    for (int o = 32; o; o >>= 1)
#pragma unroll
      for (int r = 0; r < 4; r++)
#pragma unroll
        for (int k = 0; k < KK; k++) p[r][k] += __shfl_xor(p[r][k], o, 64);

    // ---- phase 2: f32 argmin, one CB sweep for 4 rows, top-2 gap ----
    float m2[4][8];
#pragma unroll
    for (int r = 0; r < 4; r++)
#pragma unroll
      for (int k = 0; k < 8; k++) m2[r][k] = (float)(-2.0 * p[r][k]);
    float s1[4] = {3.4e38f, 3.4e38f, 3.4e38f, 3.4e38f};
    float s2[4] = {3.4e38f, 3.4e38f, 3.4e38f, 3.4e38f};
    int   c1[4] = {0, 0, 0, 0};
#pragma unroll 4
    for (int m = 0; m < 16; m++) {
      int c = m * 64 + lane;
      const float4 c0 = *(const float4*)(cbbase + (size_t)c * CD);
      const float4 cx = *(const float4*)(cbbase + (size_t)c * CD + 4);
      float qv = qfb[c];
#pragma unroll
      for (int r = 0; r < 4; r++) {
        float s = qv;
        s = fmaf(c0.x, m2[r][0], s); s = fmaf(c0.y, m2[r][1], s);
        s = fmaf(c0.z, m2[r][2], s); s = fmaf(c0.w, m2[r][3], s);
        s = fmaf(cx.x, m2[r][4], s); s = fmaf(cx.y, m2[r][5], s);
        s = fmaf(cx.z, m2[r][6], s); s = fmaf(cx.w, m2[r][7], s);
        if (s < s1[r]) { s2[r] = s1[r]; s1[r] = s; c1[r] = c; }
        else           { s2[r] = fminf(s2[r], s); }
      }
    }
#pragma unroll
    for (int o = 32; o; o >>= 1) {
#pragma unroll
      for (int r = 0; r < 4; r++) {
        float os1 = __shfl_xor(s1[r], o, 64);
        int   oc1 = __shfl_xor(c1[r], o, 64);
        float os2 = __shfl_xor(s2[r], o, 64);
        float hi = fmaxf(s1[r], os1);
        s2[r] = fminf(fminf(s2[r], os2), hi);
        if (os1 < s1[r] || (os1 == s1[r] && oc1 < c1[r])) { s1[r] = os1; c1[r] = oc1; }
      }
    }

    double Ap[4], Cm[4];
    float cbf[4][8];
#pragma unroll
    for (int r = 0; r < 4; r++) {
      if (s2[r] - s1[r] < 0.03f) {     // wave-uniform, rare: exact f64 re-score
        double pm2[8];
#pragma unroll
        for (int k = 0; k < 8; k++) pm2[k] = -2.0 * p[r][k];
        double bs = 1e300; int bc = 0;
#pragma unroll 4
        for (int m = 0; m < 16; m++) {
          int c = m * 64 + lane;
          const float* cb2 = cbbase + (size_t)c * CD;
          double s = qb[c];
#pragma unroll
          for (int k = 0; k < 8; k++) s = fma((double)cb2[k], pm2[k], s);
          if (s < bs) { bs = s; bc = c; }
        }
#pragma unroll
        for (int o = 32; o; o >>= 1) {
          double obs = __shfl_xor(bs, o, 64);
          int    obc = __shfl_xor(bc, o, 64);
          if (obs < bs || (obs == bs && obc < bc)) { bs = obs; bc = obc; }
        }
        c1[r] = bc;
      }
      int cu = __builtin_amdgcn_readfirstlane(c1[r]);
      const float* cbr = cbbase + (size_t)cu * CD;
      double pz = p[r][8];                    // res.b
#pragma unroll
      for (int k = 0; k < 8; k++) {
        float cf = cbr[k];
        cbf[r][k] = cf;
        pz = fma((double)cf, p[r][k], pz);
      }
      double nt2 = qb[cu];
      double n2 = ns2[r];
      // rotation scalars via guarded rsqrt (matches max(sqrt,1e-6) semantics)
      double rns = (n2  > 1e-12) ? rsqrt(n2)  : 1e6;
      double rnt = (nt2 > 1e-12) ? rsqrt(nt2) : 1e6;
      double s_nt = nt2 * rnt;                // sqrt(nt2)
      double wn2 = n2 * rns * rns + 2.0 * pz * rns * rnt + nt2 * rnt * rnt;
      double rdwn = (wn2 > 1e-12) ? rsqrt(wn2) : 1e6;
      double eu = n2 * rns;
      double ew = (n2 * rns + pz * rnt) * rdwn;
      double scale = s_nt * rns;
      double A = scale * (1.0 - 2.0 * ew * rdwn * rns);
      double C = scale * rnt * 2.0 * (eu - ew * rdwn);
      commit += n2 - 2.0 * pz + nt2;
      double ap = 1.0 - A;
      Ap[r] = ap; Cm[r] = C;
      ns2[r] = ap * ap * n2 - 2.0 * ap * C * pz + C * C * nt2;
      if (lane == 0)
        out_codes[((size_t)bb * NCB + i) * TT + t0 + w * 4 + r] = (float)cu;
    }

    // ---- phase 3: res' = Ap*res - Cm*(b + Wn.cb), 4 rows, one pass ----
#pragma unroll
    for (int j = 0; j < 8; j++) {
      int d = j * 64 + lane;
      double wv[KK];
#pragma unroll
      for (int k = 0; k < KK; k++) wv[k] = wcur[k * DD + d];
#pragma unroll
      for (int r = 0; r < 4; r++) {
        double imp = wv[8];
#pragma unroll
        for (int k = 0; k < 8; k++) imp = fma((double)cbf[r][k], wv[k], imp);
        res[r][j] = Ap[r] * res[r][j] - Cm[r] * imp;
      }
    }
    __syncthreads();   // joins waves + drains next-stage DMA (vmcnt 0)
  }

  // ---- commit: wave-uniform already; lane 0 holds the wave total ----
  if (lane == 0) cbuf[w] = commit;

  // ---- z_q = z - res_final : transpose via LDS (buf[1]), store coalesced ----
#pragma unroll
  for (int r = 0; r < 4; r++)
#pragma unroll
    for (int j = 0; j < 8; j++)
      tile[(j * 64 + lane) * 17 + (w * 4 + r)] = (float)res[r][j];
  __syncthreads();   // covers cbuf too
#pragma unroll
  for (int m = 0; m < 8; m++) {
    int F = tid + m * 256, d = F >> 2, qq = F & 3;
    const float4 v = *(const float4*)(zb + (size_t)d * TT + qq * 4);
    float4 o;
    o.x = v.x - tile[d * 17 + qq * 4 + 0];
    o.y = v.y - tile[d * 17 + qq * 4 + 1];
    o.z = v.z - tile[d * 17 + qq * 4 + 2];
    o.w = v.w - tile[d * 17 + qq * 4 + 3];
    *(float4*)(out_zq + ((size_t)bb * DD + d) * TT + t0 + qq * 4) = o;
  }
  if (tid == 0)
    partials[blockIdx.x] = cbuf[0] + cbuf[1] + cbuf[2] + cbuf[3];
}

__global__ void k_fin(const double* __restrict__ partials, float* __restrict__ outc) {
  __shared__ double sb[4];
  int tid = threadIdx.x, lane = tid & 63, w = tid >> 6;
  double s = 0.0;
#pragma unroll
  for (int m = 0; m < NBLK / 256; m++) s += partials[tid + m * 256];
#pragma unroll
  for (int o = 32; o; o >>= 1) s += __shfl_xor(s, o, 64);
  if (lane == 0) sb[w] = s;
  __syncthreads();
  if (tid == 0) {
    double tot = sb[0] + sb[1] + sb[2] + sb[3];
    outc[0] = (float)(tot * 1.25 / (double)((size_t)NB * TT * DD));
  }
}

extern "C" void kernel_launch(void* const* d_in, const int* in_sizes, int n_in,
                              void* d_out, int out_size, void* d_ws, size_t ws_size,
                              hipStream_t stream) {
  const float* z  = (const float*)d_in[0];
  const float* V  = (const float*)d_in[1];
  const float* g  = (const float*)d_in[2];
  const float* b  = (const float*)d_in[3];
  const float* CB = (const float*)d_in[4];
  float* out = (float*)d_out;

  double* parts = (double*)d_ws;
  double* wn  = (double*)((char*)d_ws + WS_WN_OFF);
  double* q   = (double*)((char*)d_ws + WS_Q_OFF);
  float*  qf  = (float*)((char*)d_ws + WS_QF_OFF);

  hipLaunchKernelGGL(k_wn, dim3((NCB * DD + 255) / 256), dim3(256), 0, stream, V, g, b, wn);
  hipLaunchKernelGGL(k_q, dim3((NCB * CS) / 4), dim3(256), 0, stream, CB, b, wn, q, qf);
  hipLaunchKernelGGL(k_main, dim3(NBLK), dim3(256), 0, stream,
                     z, CB, wn, q, qf,
                     out, out + (size_t)NB * DD * TT, parts);
  hipLaunchKernelGGL(k_fin, dim3(1), dim3(256), 0, stream,
                     parts, out + (size_t)NB * DD * TT + (size_t)NB * NCB * TT);
}

// Round 6
// 680.194 us; speedup vs baseline: 1.4412x; 1.4412x over previous
//
#include <hip/hip_runtime.h>

// ResidualSimVQ eval forward — R6: f32 reduced-p (fallback re-derives f64),
// fused 4-row argmin, DMA double-buffered d-major Wn, split select chains.
// implicit_c = CB_c @ Wn^T + b (rank 8) => argmin needs only p = res@[Wn|b].
// Scoring is affine-invariant: s' = q/2 - sum(cb*p) (qf stores q/2, p stored
// negated f32) => same argmin as q - 2 sum(cb*p). Gap threshold 0.015 (half
// scale). Ambiguous rows (gap < thr) re-sweep Wn in f64 and score exactly.
// res chain stays f64; pz computed f64 from f32 p (drift ~1e-8, safe).
// rot = A*res + C*zq; res' = (1-A)res - C*zq; ns2 by recurrence; nt2 = qtab.
// commit is wave-uniform -> lane 0's copy IS the wave total (no reduction).

#define NB  16
#define DD  512
#define TT  2048
#define NCB 9
#define CS  1024
#define CD  8
#define KK  9   // CD + 1: col 8 of the d-major table is the bias b
#define NBLK (NB * (TT / 16))   // 2048 k_main blocks
#define STGB (KK * DD * 8)      // 36864 B per stage table
#define GAPTHR 0.015f

#define WS_WN_OFF  16384                               // f64 [Wn|b], d-major [i][d][k]
#define WS_Q_OFF   (WS_WN_OFF + (size_t)NCB*KK*DD*8)   // f64 ||implicit||^2
#define WS_QF_OFF  (WS_Q_OFF  + (size_t)NCB*CS*8)      // f32 0.5*||implicit||^2

__device__ __forceinline__ void ld_lds16(const void* g, void* l) {
  __builtin_amdgcn_global_load_lds(
      (const __attribute__((address_space(1))) void*)g,
      (__attribute__((address_space(3))) void*)l, 16, 0, 0);
}

__global__ void k_wn(const float* __restrict__ V, const float* __restrict__ g,
                     const float* __restrict__ bp, double* __restrict__ wn) {
  int gid = blockIdx.x * 256 + threadIdx.x;
  if (gid >= NCB * DD) return;
  int i = gid / DD, d = gid % DD;
  const float* vp = V + (size_t)gid * CD;
  double v[CD], s = 0.0;
#pragma unroll
  for (int k = 0; k < CD; k++) { v[k] = (double)vp[k]; s = fma(v[k], v[k], s); }
  double den = fmax(sqrt(s), 1e-12);
  double gg = (double)g[gid];
  double* row = wn + ((size_t)i * DD + d) * KK;
#pragma unroll
  for (int k = 0; k < CD; k++) row[k] = gg * v[k] / den;
  row[CD] = (double)bp[gid];   // bias col
}

__global__ void k_q(const float* __restrict__ CBp, const float* __restrict__ bp,
                    const double* __restrict__ wn,
                    double* __restrict__ q, float* __restrict__ qf) {
  int wid = blockIdx.x * 4 + (threadIdx.x >> 6);
  int lane = threadIdx.x & 63;
  int i = wid / CS, c = wid % CS;
  const float* cb = CBp + (size_t)(i * CS + c) * CD;
  double cbv[CD];
#pragma unroll
  for (int k = 0; k < CD; k++) cbv[k] = (double)cb[k];
  const double* wnp = wn + (size_t)i * DD * KK;
  const float* bb = bp + (size_t)i * DD;
  double acc = 0.0;
#pragma unroll
  for (int j = 0; j < 8; j++) {
    int d = j * 64 + lane;
    double imp = (double)bb[d];
#pragma unroll
    for (int k = 0; k < CD; k++) imp = fma(cbv[k], wnp[(size_t)d * KK + k], imp);
    acc = fma(imp, imp, acc);
  }
#pragma unroll
  for (int o = 32; o; o >>= 1) acc += __shfl_xor(acc, o, 64);
  if (lane == 0) { q[wid] = acc; qf[wid] = (float)(0.5 * acc); }
}

__launch_bounds__(256, 2)
__global__ void k_main(const float* __restrict__ z, const float* __restrict__ CBp,
                       const double* __restrict__ wn, const double* __restrict__ qtab,
                       const float* __restrict__ qftab,
                       float* __restrict__ out_zq, float* __restrict__ out_codes,
                       double* __restrict__ partials) {
  __shared__ __align__(16) double buf[2][KK * DD];   // 2 x 36864 B
  __shared__ double cbuf[4];
  float* tile = (float*)buf[1];                      // 34816 B fits in buf[1]

  const int tid = threadIdx.x, lane = tid & 63, w = tid >> 6;
  const int bb = blockIdx.x >> 7, tg = blockIdx.x & 127;
  const int t0 = tg * 16;
  const float* zb = z + (size_t)bb * DD * TT + t0;
  const char* wnb = (const char*)wn;

  // ---- prologue: DMA stage-0 table into buf[0]; transpose z tile in buf[1] --
#pragma unroll
  for (int m = 0; m < 9; m++)
    ld_lds16(wnb + (size_t)w * 9216 + m * 1024 + lane * 16,
             (char*)buf[0] + w * 9216 + m * 1024);
#pragma unroll
  for (int m = 0; m < 8; m++) {
    int F = tid + m * 256, d = F >> 2, qq = F & 3;
    const float4 v = *(const float4*)(zb + (size_t)d * TT + qq * 4);
    tile[d * 17 + qq * 4 + 0] = v.x; tile[d * 17 + qq * 4 + 1] = v.y;
    tile[d * 17 + qq * 4 + 2] = v.z; tile[d * 17 + qq * 4 + 3] = v.w;
  }
  __syncthreads();   // tile written; stage-0 DMA drained (vmcnt 0 at barrier)

  double res[4][8], ns2[4];
#pragma unroll
  for (int r = 0; r < 4; r++) {
    double s = 0.0;
#pragma unroll
    for (int j = 0; j < 8; j++) {
      res[r][j] = (double)tile[(j * 64 + lane) * 17 + (w * 4 + r)];
      s = fma(res[r][j], res[r][j], s);
    }
    ns2[r] = s;
  }
#pragma unroll
  for (int o = 32; o; o >>= 1)
#pragma unroll
    for (int r = 0; r < 4; r++) ns2[r] += __shfl_xor(ns2[r], o, 64);
  __syncthreads();   // tile reads done -> buf[1] free for stage-1 DMA

  double commit = 0.0;

  for (int i = 0; i < NCB; i++) {
    const double* wcur = buf[i & 1];
    // ---- prefetch next stage table (DMA, overlaps compute) ----
    if (i < NCB - 1) {
      const char* src = wnb + (size_t)(i + 1) * STGB;
#pragma unroll
      for (int m = 0; m < 9; m++)
        ld_lds16(src + (size_t)w * 9216 + m * 1024 + lane * 16,
                 (char*)buf[(i + 1) & 1] + w * 9216 + m * 1024);
    }

    const float* cbbase = CBp + (size_t)i * CS * CD;
    const float* qfb = qftab + i * CS;
    const double* qb = qtab + i * CS;

    // ---- phase 1: per-lane f64 partials over own 8 d's, 2-row pairs;
    //      store negated f32 (score = q/2 - sum cb*p needs -p) ----
    float pf[4][KK];
#pragma unroll
    for (int pr = 0; pr < 2; pr++) {
      double pp[2][KK];
#pragma unroll
      for (int u = 0; u < 2; u++)
#pragma unroll
        for (int k = 0; k < KK; k++) pp[u][k] = 0.0;
#pragma unroll
      for (int j = 0; j < 8; j++) {
        const double* wrow = wcur + (size_t)(j * 64 + lane) * KK;
        double wv[KK];
#pragma unroll
        for (int k = 0; k < KK; k++) wv[k] = wrow[k];
#pragma unroll
        for (int u = 0; u < 2; u++) {
          double rv = res[2 * pr + u][j];
#pragma unroll
          for (int k = 0; k < KK; k++) pp[u][k] = fma(rv, wv[k], pp[u][k]);
        }
      }
#pragma unroll
      for (int u = 0; u < 2; u++)
#pragma unroll
        for (int k = 0; k < KK; k++) pf[2 * pr + u][k] = -(float)pp[u][k];
    }
    // cross-lane reduce in f32 (6 levels, 36 values)
#pragma unroll
    for (int o = 32; o; o >>= 1)
#pragma unroll
      for (int r = 0; r < 4; r++)
#pragma unroll
        for (int k = 0; k < KK; k++) pf[r][k] += __shfl_xor(pf[r][k], o, 64);

    // ---- phase 2: f32 argmin, one CB sweep, split even/odd chains ----
    float s1a[4], s2a[4], s1b[4], s2b[4];
    int   c1a[4], c1b[4];
#pragma unroll
    for (int r = 0; r < 4; r++) {
      s1a[r] = s2a[r] = s1b[r] = s2b[r] = 3.4e38f;
      c1a[r] = c1b[r] = 0;
    }
#pragma unroll 4
    for (int m = 0; m < 16; m += 2) {
#pragma unroll
      for (int h = 0; h < 2; h++) {
        int c = (m + h) * 64 + lane;
        const float4 c0 = *(const float4*)(cbbase + (size_t)c * CD);
        const float4 cx = *(const float4*)(cbbase + (size_t)c * CD + 4);
        float qv = qfb[c];
#pragma unroll
        for (int r = 0; r < 4; r++) {
          float s = qv;
          s = fmaf(c0.x, pf[r][0], s); s = fmaf(c0.y, pf[r][1], s);
          s = fmaf(c0.z, pf[r][2], s); s = fmaf(c0.w, pf[r][3], s);
          s = fmaf(cx.x, pf[r][4], s); s = fmaf(cx.y, pf[r][5], s);
          s = fmaf(cx.z, pf[r][6], s); s = fmaf(cx.w, pf[r][7], s);
          if (h == 0) {
            if (s < s1a[r]) { s2a[r] = s1a[r]; s1a[r] = s; c1a[r] = c; }
            else            { s2a[r] = fminf(s2a[r], s); }
          } else {
            if (s < s1b[r]) { s2b[r] = s1b[r]; s1b[r] = s; c1b[r] = c; }
            else            { s2b[r] = fminf(s2b[r], s); }
          }
        }
      }
    }
    // merge chains (min-index on ties), then cross-lane top-2 merge
    float s1[4], s2[4]; int c1[4];
#pragma unroll
    for (int r = 0; r < 4; r++) {
      if (s1a[r] < s1b[r] || (s1a[r] == s1b[r] && c1a[r] < c1b[r])) {
        s1[r] = s1a[r]; c1[r] = c1a[r]; s2[r] = fminf(s2a[r], s1b[r]);
      } else {
        s1[r] = s1b[r]; c1[r] = c1b[r]; s2[r] = fminf(s2b[r], s1a[r]);
      }
    }
#pragma unroll
    for (int o = 32; o; o >>= 1) {
#pragma unroll
      for (int r = 0; r < 4; r++) {
        float os1 = __shfl_xor(s1[r], o, 64);
        int   oc1 = __shfl_xor(c1[r], o, 64);
        float os2 = __shfl_xor(s2[r], o, 64);
        float hi = fmaxf(s1[r], os1);
        s2[r] = fminf(fminf(s2[r], os2), hi);
        if (os1 < s1[r] || (os1 == s1[r] && oc1 < c1[r])) { s1[r] = os1; c1[r] = oc1; }
      }
    }

    // ---- per-row: rare exact-f64 fallback, scalars ----
    double Ap[4], Cm[4], cbv[4][8];
#pragma unroll
    for (int r = 0; r < 4; r++) {
      if (s2[r] - s1[r] < GAPTHR) {   // wave-uniform, rare: full f64 re-derive
        double pd[KK];
#pragma unroll
        for (int k = 0; k < KK; k++) pd[k] = 0.0;
#pragma unroll
        for (int j = 0; j < 8; j++) {
          const double* wrow = wcur + (size_t)(j * 64 + lane) * KK;
          double rv = res[r][j];
#pragma unroll
          for (int k = 0; k < KK; k++) pd[k] = fma(rv, wrow[k], pd[k]);
        }
#pragma unroll
        for (int o = 32; o; o >>= 1)
#pragma unroll
          for (int k = 0; k < KK; k++) pd[k] += __shfl_xor(pd[k], o, 64);
        double pm2[8];
#pragma unroll
        for (int k = 0; k < 8; k++) pm2[k] = -2.0 * pd[k];
        double bs = 1e300; int bc = 0;
#pragma unroll 4
        for (int m = 0; m < 16; m++) {
          int c = m * 64 + lane;
          const float* cb2 = cbbase + (size_t)c * CD;
          double s = qb[c];
#pragma unroll
          for (int k = 0; k < 8; k++) s = fma((double)cb2[k], pm2[k], s);
          if (s < bs) { bs = s; bc = c; }
        }
#pragma unroll
        for (int o = 32; o; o >>= 1) {
          double obs = __shfl_xor(bs, o, 64);
          int    obc = __shfl_xor(bc, o, 64);
          if (obs < bs || (obs == bs && obc < bc)) { bs = obs; bc = obc; }
        }
        c1[r] = bc;
      }
      int cu = __builtin_amdgcn_readfirstlane(c1[r]);
      const float* cbr = cbbase + (size_t)cu * CD;
      // pz from f32 p (negated): pz = -(pf8 + sum cb*pfk), f64 arithmetic
      double pzn = (double)pf[r][8];
#pragma unroll
      for (int k = 0; k < 8; k++) {
        double cf = (double)cbr[k];
        cbv[r][k] = cf;
        pzn = fma(cf, (double)pf[r][k], pzn);
      }
      double pz = -pzn;
      double nt2 = qb[cu];
      double n2 = ns2[r];
      double rns = (n2  > 1e-12) ? rsqrt(n2)  : 1e6;
      double rnt = (nt2 > 1e-12) ? rsqrt(nt2) : 1e6;
      double s_nt = nt2 * rnt;                // sqrt(nt2)
      double wn2 = n2 * rns * rns + 2.0 * pz * rns * rnt + nt2 * rnt * rnt;
      double rdwn = (wn2 > 1e-12) ? rsqrt(wn2) : 1e6;
      double eu = n2 * rns;
      double ew = (n2 * rns + pz * rnt) * rdwn;
      double scale = s_nt * rns;
      double A = scale * (1.0 - 2.0 * ew * rdwn * rns);
      double C = scale * rnt * 2.0 * (eu - ew * rdwn);
      commit += n2 - 2.0 * pz + nt2;
      double ap = 1.0 - A;
      Ap[r] = ap; Cm[r] = C;
      ns2[r] = ap * ap * n2 - 2.0 * ap * C * pz + C * C * nt2;
      if (lane == 0)
        out_codes[((size_t)bb * NCB + i) * TT + t0 + w * 4 + r] = (float)cu;
    }

    // ---- phase 3: res' = Ap*res - Cm*(b + Wn.cb), 4 rows, one pass ----
#pragma unroll
    for (int j = 0; j < 8; j++) {
      const double* wrow = wcur + (size_t)(j * 64 + lane) * KK;
      double wv[KK];
#pragma unroll
      for (int k = 0; k < KK; k++) wv[k] = wrow[k];
#pragma unroll
      for (int r = 0; r < 4; r++) {
        double imp = wv[8];
#pragma unroll
        for (int k = 0; k < 8; k++) imp = fma(cbv[r][k], wv[k], imp);
        res[r][j] = Ap[r] * res[r][j] - Cm[r] * imp;
      }
    }
    __syncthreads();   // joins waves + drains next-stage DMA
  }

  // ---- commit: wave-uniform already; lane 0 holds the wave total ----
  if (lane == 0) cbuf[w] = commit;

  // ---- z_q = z - res_final : transpose via LDS (buf[1]), store coalesced ----
#pragma unroll
  for (int r = 0; r < 4; r++)
#pragma unroll
    for (int j = 0; j < 8; j++)
      tile[(j * 64 + lane) * 17 + (w * 4 + r)] = (float)res[r][j];
  __syncthreads();   // covers cbuf too
#pragma unroll
  for (int m = 0; m < 8; m++) {
    int F = tid + m * 256, d = F >> 2, qq = F & 3;
    const float4 v = *(const float4*)(zb + (size_t)d * TT + qq * 4);
    float4 o;
    o.x = v.x - tile[d * 17 + qq * 4 + 0];
    o.y = v.y - tile[d * 17 + qq * 4 + 1];
    o.z = v.z - tile[d * 17 + qq * 4 + 2];
    o.w = v.w - tile[d * 17 + qq * 4 + 3];
    *(float4*)(out_zq + ((size_t)bb * DD + d) * TT + t0 + qq * 4) = o;
  }
  if (tid == 0)
    partials[blockIdx.x] = cbuf[0] + cbuf[1] + cbuf[2] + cbuf[3];
}

__global__ void k_fin(const double* __restrict__ partials, float* __restrict__ outc) {
  __shared__ double sb[4];
  int tid = threadIdx.x, lane = tid & 63, w = tid >> 6;
  double s = 0.0;
#pragma unroll
  for (int m = 0; m < NBLK / 256; m++) s += partials[tid + m * 256];
#pragma unroll
  for (int o = 32; o; o >>= 1) s += __shfl_xor(s, o, 64);
  if (lane == 0) sb[w] = s;
  __syncthreads();
  if (tid == 0) {
    double tot = sb[0] + sb[1] + sb[2] + sb[3];
    outc[0] = (float)(tot * 1.25 / (double)((size_t)NB * TT * DD));
  }
}

extern "C" void kernel_launch(void* const* d_in, const int* in_sizes, int n_in,
                              void* d_out, int out_size, void* d_ws, size_t ws_size,
                              hipStream_t stream) {
  const float* z  = (const float*)d_in[0];
  const float* V  = (const float*)d_in[1];
  const float* g  = (const float*)d_in[2];
  const float* b  = (const float*)d_in[3];
  const float* CB = (const float*)d_in[4];
  float* out = (float*)d_out;

  double* parts = (double*)d_ws;
  double* wn  = (double*)((char*)d_ws + WS_WN_OFF);
  double* q   = (double*)((char*)d_ws + WS_Q_OFF);
  float*  qf  = (float*)((char*)d_ws + WS_QF_OFF);

  hipLaunchKernelGGL(k_wn, dim3((NCB * DD + 255) / 256), dim3(256), 0, stream, V, g, b, wn);
  hipLaunchKernelGGL(k_q, dim3((NCB * CS) / 4), dim3(256), 0, stream, CB, b, wn, q, qf);
  hipLaunchKernelGGL(k_main, dim3(NBLK), dim3(256), 0, stream,
                     z, CB, wn, q, qf,
                     out, out + (size_t)NB * DD * TT, parts);
  hipLaunchKernelGGL(k_fin, dim3(1), dim3(256), 0, stream,
                     parts, out + (size_t)NB * DD * TT + (size_t)NB * NCB * TT);
}

// Round 7
// 617.782 us; speedup vs baseline: 1.5868x; 1.1010x over previous
//
#include <hip/hip_runtime.h>

// ResidualSimVQ eval forward — R7: f32 Wn path (LDS halved, f32 FMA rate),
// f64 res chain, exact-f64 global fallback for ambiguous argmins.
// implicit_c = CB_c @ Wn^T + b (rank 8) => argmin needs only p = res@[Wn|b].
// Scoring: s' = q/2 + sum(cb * (-p)) (qf stores q/2, pf holds -p in f32);
// affine-equivalent to d2. Gap < 0.015 (rare, wave-uniform) -> re-derive p in
// f64 from the global f64 Wn table and score exactly (protects all decisions
// against f32 rounding).  Precision note: the f32 STORAGE of Wn perturbs the
// res chain by ~2e-7 abs over 9 stages — 5x below the f32 reference's own
// rounding noise (~1e-6 rel), which the argmin margins already tolerate.
// rot = A*res + C*zq; res' = (1-A)res - C*zq; ns2 by recurrence; nt2 = qtab.
// commit is wave-uniform -> lane 0's copy IS the wave total (no reduction).

#define NB  16
#define DD  512
#define TT  2048
#define NCB 9
#define CS  1024
#define CD  8
#define KK  9   // CD + 1: slot 8 is the bias b
#define NBLK (NB * (TT / 16))   // 2048 k_main blocks
#define STGF (KK * DD * 4)      // 18432 B per f32 stage table
#define GAPTHR 0.015f

#define WS_WN_OFF  16384                                 // f64 [Wn|b], d-major [i][d][k] (fallback)
#define WS_WNF_OFF (WS_WN_OFF  + (size_t)NCB*DD*KK*8)    // f32 [Wn|b], k-major [i][k][d] (DMA)
#define WS_Q_OFF   (WS_WNF_OFF + (size_t)NCB*DD*KK*4)    // f64 ||implicit||^2
#define WS_QF_OFF  (WS_Q_OFF   + (size_t)NCB*CS*8)       // f32 0.5*||implicit||^2

__device__ __forceinline__ void ld_lds16(const void* g, void* l) {
  __builtin_amdgcn_global_load_lds(
      (const __attribute__((address_space(1))) void*)g,
      (__attribute__((address_space(3))) void*)l, 16, 0, 0);
}

__global__ void k_wn(const float* __restrict__ V, const float* __restrict__ g,
                     const float* __restrict__ bp, double* __restrict__ wn,
                     float* __restrict__ wnf) {
  int gid = blockIdx.x * 256 + threadIdx.x;
  if (gid >= NCB * DD) return;
  int i = gid / DD, d = gid % DD;
  const float* vp = V + (size_t)gid * CD;
  double v[CD], s = 0.0;
#pragma unroll
  for (int k = 0; k < CD; k++) { v[k] = (double)vp[k]; s = fma(v[k], v[k], s); }
  double den = fmax(sqrt(s), 1e-12);
  double gg = (double)g[gid];
  double* row = wn + ((size_t)i * DD + d) * KK;
  float* fb = wnf + (size_t)i * KK * DD;
#pragma unroll
  for (int k = 0; k < CD; k++) {
    double wv = gg * v[k] / den;
    row[k] = wv;
    fb[(size_t)k * DD + d] = (float)wv;   // k-major f32
  }
  row[CD] = (double)bp[gid];
  fb[(size_t)CD * DD + d] = bp[gid];
}

__global__ void k_q(const float* __restrict__ CBp, const float* __restrict__ bp,
                    const double* __restrict__ wn,
                    double* __restrict__ q, float* __restrict__ qf) {
  int wid = blockIdx.x * 4 + (threadIdx.x >> 6);
  int lane = threadIdx.x & 63;
  int i = wid / CS, c = wid % CS;
  const float* cb = CBp + (size_t)(i * CS + c) * CD;
  double cbv[CD];
#pragma unroll
  for (int k = 0; k < CD; k++) cbv[k] = (double)cb[k];
  const double* wnp = wn + (size_t)i * DD * KK;
  const float* bb = bp + (size_t)i * DD;
  double acc = 0.0;
#pragma unroll
  for (int j = 0; j < 8; j++) {
    int d = j * 64 + lane;
    double imp = (double)bb[d];
#pragma unroll
    for (int k = 0; k < CD; k++) imp = fma(cbv[k], wnp[(size_t)d * KK + k], imp);
    acc = fma(imp, imp, acc);
  }
#pragma unroll
  for (int o = 32; o; o >>= 1) acc += __shfl_xor(acc, o, 64);
  if (lane == 0) { q[wid] = acc; qf[wid] = (float)(0.5 * acc); }
}

__launch_bounds__(256, 2)
__global__ void k_main(const float* __restrict__ z, const float* __restrict__ CBp,
                       const double* __restrict__ wn, const float* __restrict__ wnf,
                       const double* __restrict__ qtab, const float* __restrict__ qftab,
                       float* __restrict__ out_zq, float* __restrict__ out_codes,
                       double* __restrict__ partials) {
  __shared__ __align__(16) float wbuf[2][KK * DD];   // 2 x 18432 B
  __shared__ double cbuf[4];
  float* tile = (float*)wbuf;                        // 34816 B <= 36864 B

  const int tid = threadIdx.x, lane = tid & 63, w = tid >> 6;
  const int bb = blockIdx.x >> 7, tg = blockIdx.x & 127;
  const int t0 = tg * 16;
  const float* zb = z + (size_t)bb * DD * TT + t0;
  const char* wfb = (const char*)wnf;

  // ---- prologue: transpose z tile (whole LDS), read res, then DMA stage 0 --
#pragma unroll
  for (int m = 0; m < 8; m++) {
    int F = tid + m * 256, d = F >> 2, qq = F & 3;
    const float4 v = *(const float4*)(zb + (size_t)d * TT + qq * 4);
    tile[d * 17 + qq * 4 + 0] = v.x; tile[d * 17 + qq * 4 + 1] = v.y;
    tile[d * 17 + qq * 4 + 2] = v.z; tile[d * 17 + qq * 4 + 3] = v.w;
  }
  __syncthreads();

  double res[4][8], ns2[4];
#pragma unroll
  for (int r = 0; r < 4; r++) {
    double s = 0.0;
#pragma unroll
    for (int j = 0; j < 8; j++) {
      res[r][j] = (double)tile[(j * 64 + lane) * 17 + (w * 4 + r)];
      s = fma(res[r][j], res[r][j], s);
    }
    ns2[r] = s;
  }
#pragma unroll
  for (int o = 32; o; o >>= 1)
#pragma unroll
    for (int r = 0; r < 4; r++) ns2[r] += __shfl_xor(ns2[r], o, 64);
  __syncthreads();   // tile consumed -> LDS free

  // DMA stage-0 f32 table into wbuf[0]: 18 KiB = 18 wave-calls (waves 0,1: 5)
#pragma unroll
  for (int m = 0; m < 4; m++)
    ld_lds16(wfb + (w + m * 4) * 1024 + lane * 16,
             (char*)wbuf[0] + (w + m * 4) * 1024);
  if (w < 2)
    ld_lds16(wfb + (w + 16) * 1024 + lane * 16,
             (char*)wbuf[0] + (w + 16) * 1024);
  __syncthreads();   // drains DMA (vmcnt 0 at barrier)

  double commit = 0.0;

  for (int i = 0; i < NCB; i++) {
    const float* wcur = wbuf[i & 1];
    // ---- prefetch next stage f32 table (DMA, overlaps compute) ----
    if (i < NCB - 1) {
      const char* src = wfb + (size_t)(i + 1) * STGF;
      char* dst = (char*)wbuf[(i + 1) & 1];
#pragma unroll
      for (int m = 0; m < 4; m++)
        ld_lds16(src + (w + m * 4) * 1024 + lane * 16, dst + (w + m * 4) * 1024);
      if (w < 2)
        ld_lds16(src + (w + 16) * 1024 + lane * 16, dst + (w + 16) * 1024);
    }

    const float* cbbase = CBp + (size_t)i * CS * CD;
    const float* qfb = qftab + i * CS;
    const double* qb = qtab + i * CS;

    // ---- phase 1: pf[r][k] = -(res . [Wn|b]) in f32, one pass, 4 rows ----
    float pf[4][KK];
#pragma unroll
    for (int r = 0; r < 4; r++)
#pragma unroll
      for (int k = 0; k < KK; k++) pf[r][k] = 0.0f;
#pragma unroll
    for (int j = 0; j < 8; j++) {
      int d = j * 64 + lane;
      float wv[KK];
#pragma unroll
      for (int k = 0; k < KK; k++) wv[k] = wcur[k * DD + d];
      float rv[4];
#pragma unroll
      for (int r = 0; r < 4; r++) rv[r] = -(float)res[r][j];
#pragma unroll
      for (int r = 0; r < 4; r++)
#pragma unroll
        for (int k = 0; k < KK; k++) pf[r][k] = fmaf(rv[r], wv[k], pf[r][k]);
    }
#pragma unroll
    for (int o = 32; o; o >>= 1)
#pragma unroll
      for (int r = 0; r < 4; r++)
#pragma unroll
        for (int k = 0; k < KK; k++) pf[r][k] += __shfl_xor(pf[r][k], o, 64);

    // ---- phase 2: f32 argmin, one CB sweep, split even/odd chains ----
    float s1a[4], s2a[4], s1b[4], s2b[4];
    int   c1a[4], c1b[4];
#pragma unroll
    for (int r = 0; r < 4; r++) {
      s1a[r] = s2a[r] = s1b[r] = s2b[r] = 3.4e38f;
      c1a[r] = c1b[r] = 0;
    }
#pragma unroll 4
    for (int m = 0; m < 16; m += 2) {
#pragma unroll
      for (int h = 0; h < 2; h++) {
        int c = (m + h) * 64 + lane;
        const float4 c0 = *(const float4*)(cbbase + (size_t)c * CD);
        const float4 cx = *(const float4*)(cbbase + (size_t)c * CD + 4);
        float qv = qfb[c];
#pragma unroll
        for (int r = 0; r < 4; r++) {
          float s = qv;
          s = fmaf(c0.x, pf[r][0], s); s = fmaf(c0.y, pf[r][1], s);
          s = fmaf(c0.z, pf[r][2], s); s = fmaf(c0.w, pf[r][3], s);
          s = fmaf(cx.x, pf[r][4], s); s = fmaf(cx.y, pf[r][5], s);
          s = fmaf(cx.z, pf[r][6], s); s = fmaf(cx.w, pf[r][7], s);
          if (h == 0) {
            if (s < s1a[r]) { s2a[r] = s1a[r]; s1a[r] = s; c1a[r] = c; }
            else            { s2a[r] = fminf(s2a[r], s); }
          } else {
            if (s < s1b[r]) { s2b[r] = s1b[r]; s1b[r] = s; c1b[r] = c; }
            else            { s2b[r] = fminf(s2b[r], s); }
          }
        }
      }
    }
    float s1[4], s2[4]; int c1[4];
#pragma unroll
    for (int r = 0; r < 4; r++) {
      if (s1a[r] < s1b[r] || (s1a[r] == s1b[r] && c1a[r] < c1b[r])) {
        s1[r] = s1a[r]; c1[r] = c1a[r]; s2[r] = fminf(s2a[r], s1b[r]);
      } else {
        s1[r] = s1b[r]; c1[r] = c1b[r]; s2[r] = fminf(s2b[r], s1a[r]);
      }
    }
#pragma unroll
    for (int o = 32; o; o >>= 1) {
#pragma unroll
      for (int r = 0; r < 4; r++) {
        float os1 = __shfl_xor(s1[r], o, 64);
        int   oc1 = __shfl_xor(c1[r], o, 64);
        float os2 = __shfl_xor(s2[r], o, 64);
        float hi = fmaxf(s1[r], os1);
        s2[r] = fminf(fminf(s2[r], os2), hi);
        if (os1 < s1[r] || (os1 == s1[r] && oc1 < c1[r])) { s1[r] = os1; c1[r] = oc1; }
      }
    }

    // ---- per-row: rare exact-f64 fallback (global Wn), rotation scalars ----
    double Ap[4], Cm[4];
    float cbf[4][8];
#pragma unroll
    for (int r = 0; r < 4; r++) {
      if (s2[r] - s1[r] < GAPTHR) {   // wave-uniform, rare
        double pd[KK];
#pragma unroll
        for (int k = 0; k < KK; k++) pd[k] = 0.0;
#pragma unroll
        for (int j = 0; j < 8; j++) {
          const double* wrow = wn + ((size_t)i * DD + j * 64 + lane) * KK;
          double rv = res[r][j];
#pragma unroll
          for (int k = 0; k < KK; k++) pd[k] = fma(rv, wrow[k], pd[k]);
        }
#pragma unroll
        for (int o = 32; o; o >>= 1)
#pragma unroll
          for (int k = 0; k < KK; k++) pd[k] += __shfl_xor(pd[k], o, 64);
        double pm2[8];
#pragma unroll
        for (int k = 0; k < 8; k++) pm2[k] = -2.0 * pd[k];
        double bs = 1e300; int bc = 0;
#pragma unroll 4
        for (int m = 0; m < 16; m++) {
          int c = m * 64 + lane;
          const float* cb2 = cbbase + (size_t)c * CD;
          double s = qb[c];
#pragma unroll
          for (int k = 0; k < 8; k++) s = fma((double)cb2[k], pm2[k], s);
          if (s < bs) { bs = s; bc = c; }
        }
#pragma unroll
        for (int o = 32; o; o >>= 1) {
          double obs = __shfl_xor(bs, o, 64);
          int    obc = __shfl_xor(bc, o, 64);
          if (obs < bs || (obs == bs && obc < bc)) { bs = obs; bc = obc; }
        }
        c1[r] = bc;
      }
      int cu = __builtin_amdgcn_readfirstlane(c1[r]);
      const float* cbr = cbbase + (size_t)cu * CD;
      double pzn = (double)pf[r][8];
#pragma unroll
      for (int k = 0; k < 8; k++) {
        float cf = cbr[k];
        cbf[r][k] = cf;
        pzn = fma((double)cf, (double)pf[r][k], pzn);
      }
      double pz = -pzn;
      double nt2 = qb[cu];
      double n2 = ns2[r];
      double rns = (n2  > 1e-12) ? rsqrt(n2)  : 1e6;
      double rnt = (nt2 > 1e-12) ? rsqrt(nt2) : 1e6;
      double s_nt = nt2 * rnt;                // sqrt(nt2)
      double wn2 = n2 * rns * rns + 2.0 * pz * rns * rnt + nt2 * rnt * rnt;
      double rdwn = (wn2 > 1e-12) ? rsqrt(wn2) : 1e6;
      double eu = n2 * rns;
      double ew = (n2 * rns + pz * rnt) * rdwn;
      double scale = s_nt * rns;
      double A = scale * (1.0 - 2.0 * ew * rdwn * rns);
      double C = scale * rnt * 2.0 * (eu - ew * rdwn);
      commit += n2 - 2.0 * pz + nt2;
      double ap = 1.0 - A;
      Ap[r] = ap; Cm[r] = C;
      ns2[r] = ap * ap * n2 - 2.0 * ap * C * pz + C * C * nt2;
      if (lane == 0)
        out_codes[((size_t)bb * NCB + i) * TT + t0 + w * 4 + r] = (float)cu;
    }

    // ---- phase 3: res' = Ap*res - Cm*(b + Wn.cb), f32 imp, one pass ----
#pragma unroll
    for (int j = 0; j < 8; j++) {
      int d = j * 64 + lane;
      float wv[KK];
#pragma unroll
      for (int k = 0; k < KK; k++) wv[k] = wcur[k * DD + d];
#pragma unroll
      for (int r = 0; r < 4; r++) {
        float impf = wv[8];
#pragma unroll
        for (int k = 0; k < 8; k++) impf = fmaf(cbf[r][k], wv[k], impf);
        res[r][j] = Ap[r] * res[r][j] - Cm[r] * (double)impf;
      }
    }
    __syncthreads();   // joins waves + drains next-stage DMA
  }

  // ---- commit: wave-uniform already; lane 0 holds the wave total ----
  if (lane == 0) cbuf[w] = commit;

  // ---- z_q = z - res_final : transpose via LDS, store coalesced ----
#pragma unroll
  for (int r = 0; r < 4; r++)
#pragma unroll
    for (int j = 0; j < 8; j++)
      tile[(j * 64 + lane) * 17 + (w * 4 + r)] = (float)res[r][j];
  __syncthreads();   // covers cbuf too
#pragma unroll
  for (int m = 0; m < 8; m++) {
    int F = tid + m * 256, d = F >> 2, qq = F & 3;
    const float4 v = *(const float4*)(zb + (size_t)d * TT + qq * 4);
    float4 o;
    o.x = v.x - tile[d * 17 + qq * 4 + 0];
    o.y = v.y - tile[d * 17 + qq * 4 + 1];
    o.z = v.z - tile[d * 17 + qq * 4 + 2];
    o.w = v.w - tile[d * 17 + qq * 4 + 3];
    *(float4*)(out_zq + ((size_t)bb * DD + d) * TT + t0 + qq * 4) = o;
  }
  if (tid == 0)
    partials[blockIdx.x] = cbuf[0] + cbuf[1] + cbuf[2] + cbuf[3];
}

__global__ void k_fin(const double* __restrict__ partials, float* __restrict__ outc) {
  __shared__ double sb[4];
  int tid = threadIdx.x, lane = tid & 63, w = tid >> 6;
  double s = 0.0;
#pragma unroll
  for (int m = 0; m < NBLK / 256; m++) s += partials[tid + m * 256];
#pragma unroll
  for (int o = 32; o; o >>= 1) s += __shfl_xor(s, o, 64);
  if (lane == 0) sb[w] = s;
  __syncthreads();
  if (tid == 0) {
    double tot = sb[0] + sb[1] + sb[2] + sb[3];
    outc[0] = (float)(tot * 1.25 / (double)((size_t)NB * TT * DD));
  }
}

extern "C" void kernel_launch(void* const* d_in, const int* in_sizes, int n_in,
                              void* d_out, int out_size, void* d_ws, size_t ws_size,
                              hipStream_t stream) {
  const float* z  = (const float*)d_in[0];
  const float* V  = (const float*)d_in[1];
  const float* g  = (const float*)d_in[2];
  const float* b  = (const float*)d_in[3];
  const float* CB = (const float*)d_in[4];
  float* out = (float*)d_out;

  double* parts = (double*)d_ws;
  double* wn  = (double*)((char*)d_ws + WS_WN_OFF);
  float*  wnf = (float*)((char*)d_ws + WS_WNF_OFF);
  double* q   = (double*)((char*)d_ws + WS_Q_OFF);
  float*  qf  = (float*)((char*)d_ws + WS_QF_OFF);

  hipLaunchKernelGGL(k_wn, dim3((NCB * DD + 255) / 256), dim3(256), 0, stream,
                     V, g, b, wn, wnf);
  hipLaunchKernelGGL(k_q, dim3((NCB * CS) / 4), dim3(256), 0, stream, CB, b, wn, q, qf);
  hipLaunchKernelGGL(k_main, dim3(NBLK), dim3(256), 0, stream,
                     z, CB, wn, wnf, q, qf,
                     out, out + (size_t)NB * DD * TT, parts);
  hipLaunchKernelGGL(k_fin, dim3(1), dim3(256), 0, stream,
                     parts, out + (size_t)NB * DD * TT + (size_t)NB * NCB * TT);
}